// Round 5
// baseline (109.200 us; speedup 1.0000x reference)
//
#include <hip/hip_runtime.h>

// Forward collapse:
//   c = y[b]; k = argmax_k(logits[c,k] + gumbel[c,b,k]) (first max)
//   x[b,:] = L[c,k] @ z[b,:] + m[c,k,:]
//
// Round 5: single fused kernel, grid (100 ck, 2 j-halves), 256 threads.
// Each block redundantly scans all samples for its own (c,k) (cheap: y read
// filters 90% before any gumbel read), compacts matches into an LDS list,
// then runs the rotated-LDS register-tiled batched GEMV over chunks of 60
// samples with L staged once. No workspace, no global atomics, no memset,
// one graph node.

#define N_Z 128
#define N_COMP 10
#define N_CLASSES 10
#define TB 60            // samples per chunk: chosen so LDS fits 64 KB static
#define LIST_CAP 256     // bucket capacity (mean 82; P(overflow) ~ 1e-60)

__global__ __launch_bounds__(256) void k_fused(
    const float* __restrict__ z, const int* __restrict__ y,
    const float* __restrict__ gumbel, const float* __restrict__ m,
    const float* __restrict__ L, const float* __restrict__ logits,
    float* __restrict__ out, int bs)
{
    const int ck = blockIdx.x;
    const int jh = blockIdx.y;              // j range [jh*64, jh*64+64)
    const int c  = ck / N_COMP;
    const int kk = ck - c * N_COMP;
    const int t  = threadIdx.x;

    __shared__ __align__(16) float Ls[64 * 128];   // 32 KB, rotated rows
    __shared__ __align__(16) float zs[N_Z * TB];   // 30 KB, zs[i*TB+sl]
    __shared__ int list[LIST_CAP];                 // 1 KB
    __shared__ int cnt;

    if (t == 0) cnt = 0;

    // ---- stage L half (64 rows x 128), rotated: Ls[jl*128 + ((i+4jl)&127)] ----
    {
        const float4* Lg4 = (const float4*)(L + ((size_t)ck * N_Z + jh * 64) * N_Z);
        float4 lstage[8];
        #pragma unroll
        for (int p = 0; p < 8; ++p) lstage[p] = Lg4[p * 256 + t];
        #pragma unroll
        for (int p = 0; p < 8; ++p) {
            int f  = p * 256 + t;   // float4 index within the 64x128 half
            int jl = f >> 5;
            int fi = f & 31;
            int col = ((fi << 2) + 4 * jl) & 127;
            *(float4*)&Ls[jl * 128 + col] = lstage[p];
        }
    }

    // class logits (uniform per block -> scalar loads)
    float lg[N_COMP];
    #pragma unroll
    for (int i = 0; i < N_COMP; ++i) lg[i] = logits[c * N_COMP + i];

    __syncthreads();   // cnt=0 visible before atomics

    // ---- phase A: redundant selection scan over all samples ----
    for (int it = 0; it < bs / 256; ++it) {
        int b = it * 256 + t;
        if (y[b] == c) {
            const float* g = gumbel + ((size_t)c * bs + b) * N_COMP;
            float best = g[0] + lg[0];
            int bi = 0;
            #pragma unroll
            for (int k = 1; k < N_COMP; ++k) {
                float s = g[k] + lg[k];
                if (s > best) { best = s; bi = k; }  // strict > == first-max
            }
            if (bi == kk) {
                int p = atomicAdd(&cnt, 1);
                if (p < LIST_CAP) list[p] = b;
            }
        }
    }
    __syncthreads();

    const int n = min(cnt, LIST_CAP);

    const int jg  = t & 15;    // 16 j-groups, rows jl = jg + 16r
    const int sg  = t >> 4;    // 16 s-groups x 4 samples (sg==15 idle: TB=60)
    const int sl4 = sg << 2;

    const int ssl = t & 63;    // staging: sample-lane (>=TB idle)
    const int sih = t >> 6;    // staging: i-range [sih*32, sih*32+32)

    for (int s0 = 0; s0 < n; s0 += TB) {
        const int ns = min(TB, n - s0);

        // ---- stage z transposed: zs[i*TB + sl] = z[list[s0+sl]][i] ----
        if (ssl < TB) {
            int samp = list[s0 + (ssl < ns ? ssl : 0)];  // pad lanes reuse a valid id
            const float* zg = z + (size_t)samp * N_Z + sih * 32;
            #pragma unroll
            for (int q = 0; q < 8; ++q) {
                float4 v = *(const float4*)(zg + q * 4);
                int i = sih * 32 + q * 4;
                zs[(i + 0) * TB + ssl] = v.x;
                zs[(i + 1) * TB + ssl] = v.y;
                zs[(i + 2) * TB + ssl] = v.z;
                zs[(i + 3) * TB + ssl] = v.w;
            }
        }
        __syncthreads();

        if (sg < 15) {
            float acc[4][4] = {};
            #pragma unroll 2
            for (int i = 0; i < N_Z; i += 4) {
                float4 zv[4];
                #pragma unroll
                for (int ri = 0; ri < 4; ++ri)
                    zv[ri] = *(const float4*)&zs[(i + ri) * TB + sl4];
                #pragma unroll
                for (int r = 0; r < 4; ++r) {
                    int jl  = jg + 16 * r;
                    int col = (i + 4 * jl) & 127;
                    float4 lv = *(const float4*)&Ls[jl * 128 + col];
                    acc[r][0] += lv.x * zv[0].x + lv.y * zv[1].x + lv.z * zv[2].x + lv.w * zv[3].x;
                    acc[r][1] += lv.x * zv[0].y + lv.y * zv[1].y + lv.z * zv[2].y + lv.w * zv[3].y;
                    acc[r][2] += lv.x * zv[0].z + lv.y * zv[1].z + lv.z * zv[2].z + lv.w * zv[3].z;
                    acc[r][3] += lv.x * zv[0].w + lv.y * zv[1].w + lv.z * zv[2].w + lv.w * zv[3].w;
                }
            }
            // ---- epilogue: add m, scatter ----
            #pragma unroll
            for (int r = 0; r < 4; ++r) {
                int j = jh * 64 + jg + 16 * r;
                float mm = m[ck * N_Z + j];
                #pragma unroll
                for (int s = 0; s < 4; ++s) {
                    int sl = sl4 + s;
                    if (sl < ns) {
                        int samp = list[s0 + sl];
                        out[(size_t)samp * N_Z + j] = acc[r][s] + mm;
                    }
                }
            }
        }
        __syncthreads();   // before next chunk overwrites zs
    }
}

extern "C" void kernel_launch(void* const* d_in, const int* in_sizes, int n_in,
                              void* d_out, int out_size, void* d_ws, size_t ws_size,
                              hipStream_t stream)
{
    const float* z      = (const float*)d_in[0];
    const int*   y      = (const int*)d_in[1];
    const float* gumbel = (const float*)d_in[2];
    const float* m      = (const float*)d_in[3];
    const float* L      = (const float*)d_in[4];
    const float* logits = (const float*)d_in[5];
    float* out = (float*)d_out;

    const int bs = in_sizes[0] / N_Z;  // 8192

    k_fused<<<dim3(N_CLASSES * N_COMP, 2), 256, 0, stream>>>(
        z, y, gumbel, m, L, logits, out, bs);
}

// Round 6
// 101.299 us; speedup vs baseline: 1.0780x; 1.0780x over previous
//
#include <hip/hip_runtime.h>

// Forward collapse:
//   c = y[b]; k = argmax_k(logits[c,k] + gumbel[c,b,k]) (first max)
//   x[b,:] = L[c,k] @ z[b,:] + m[c,k,:]
//
// Round 6: round-4 pipeline (memset -> select -> gemm) with occupancy-fixed
// gemm: j split 4 ways (16 KB L quarter + 32 KB z = 48 KB LDS -> 3 blocks/CU),
// grid (100, 4, 4) = 1600 blocks, inactive chunks exit on one scalar load.

#define N_Z 128
#define N_COMP 10
#define N_CLASSES 10
#define N_CK (N_CLASSES * N_COMP)
#define CAP 256          // bucket capacity (mean 82, huge headroom)
#define TB 64            // samples per chunk
#define MAXCHUNK 4       // CAP / TB

// ---------------- K1: select component + direct bucket append ----------------
__global__ __launch_bounds__(256) void k_select(
    const int* __restrict__ y, const float* __restrict__ gumbel,
    const float* __restrict__ logits, int* __restrict__ counts,
    int* __restrict__ order, int bs)
{
    int b = blockIdx.x * 256 + threadIdx.x;
    if (b >= bs) return;
    int c = y[b];
    const float* g  = gumbel + ((size_t)c * bs + b) * N_COMP;
    const float* lg = logits + c * N_COMP;
    float best = g[0] + lg[0];
    int bi = 0;
    #pragma unroll
    for (int k = 1; k < N_COMP; ++k) {
        float s = g[k] + lg[k];
        if (s > best) { best = s; bi = k; }  // strict > == first-max (jnp.argmax)
    }
    int ck = c * N_COMP + bi;
    int pos = atomicAdd(&counts[ck], 1);
    if (pos < CAP) order[ck * CAP + pos] = b;
}

// ---------------- K2: per-bucket batched GEMV ----------------
// grid (100 ck, 4 j-quarters, 4 chunks), 128 threads (2 waves).
// Block computes 32 j x 64 s. Thread tile 4j (stride-8) x 4s.
// Ls quarter staged rotated: Ls[jl*128 + ((i+4*jl)&127)] = L[jq*32+jl][i]
//   -> compute reads 8 distinct rows/wave spread over all 32 banks (conflict-free).
// zs transposed: zs[i*TB + sl] -> 8 distinct float4 addrs/wave, banks 0..31 (free).
__global__ __launch_bounds__(128) void k_gemm(
    const float* __restrict__ z, const float* __restrict__ m,
    const float* __restrict__ L, const int* __restrict__ counts,
    const int* __restrict__ order, float* __restrict__ out, int bs)
{
    const int ck    = blockIdx.x;
    const int jq    = blockIdx.y;   // j range [jq*32, jq*32+32)
    const int chunk = blockIdx.z;

    const int n  = min(counts[ck], CAP);
    const int s0 = chunk * TB;
    if (s0 >= n) return;           // inactive chunk: 1 scalar load + exit
    const int ns = min(TB, n - s0);
    const int base = ck * CAP;

    __shared__ __align__(16) float Ls[32 * 128];   // 16 KB rotated quarter
    __shared__ __align__(16) float zs[N_Z * TB];   // 32 KB transposed z

    const int t = threadIdx.x;

    // ---- stage L quarter (32 rows x 128 = 1024 float4s, 128 thr x 8) ----
    {
        const float4* Lg4 = (const float4*)(L + ((size_t)ck * N_Z + jq * 32) * N_Z);
        #pragma unroll
        for (int p = 0; p < 8; ++p) {
            int f  = p * 128 + t;      // float4 index in the 32x128 quarter
            int jl = f >> 5;           // local row 0..31
            int fi = f & 31;           // float4 within row
            float4 v = Lg4[f];
            int col = ((fi << 2) + 4 * jl) & 127;
            *(float4*)&Ls[jl * 128 + col] = v;
        }
    }
    // ---- stage z transposed: zs[i*TB+sl] = z[order[base+s0+sl]][i] ----
    {
        int sl  = t & 63;
        int sih = t >> 6;   // i-half 0..1
        int samp = order[base + s0 + (sl < ns ? sl : 0)];  // pad lanes reuse slot 0
        const float* zg = z + (size_t)samp * N_Z + sih * 64;
        #pragma unroll
        for (int q = 0; q < 16; ++q) {
            float4 v = *(const float4*)(zg + q * 4);
            int i = sih * 64 + q * 4;
            zs[(i + 0) * TB + sl] = v.x;
            zs[(i + 1) * TB + sl] = v.y;
            zs[(i + 2) * TB + sl] = v.z;
            zs[(i + 3) * TB + sl] = v.w;
        }
    }
    __syncthreads();

    const int jg  = t & 7;     // 8 j-groups, local rows jl = jg + 8r (r<4)
    const int sg  = t >> 3;    // 16 s-groups x 4 samples
    const int sl4 = sg << 2;

    float acc[4][4] = {};

    #pragma unroll 2
    for (int i = 0; i < N_Z; i += 4) {
        float4 zv[4];
        #pragma unroll
        for (int ri = 0; ri < 4; ++ri)
            zv[ri] = *(const float4*)&zs[(i + ri) * TB + sl4];
        #pragma unroll
        for (int r = 0; r < 4; ++r) {
            int jl  = jg + 8 * r;
            int col = (i + 4 * jl) & 127;
            float4 lv = *(const float4*)&Ls[jl * 128 + col];
            acc[r][0] += lv.x * zv[0].x + lv.y * zv[1].x + lv.z * zv[2].x + lv.w * zv[3].x;
            acc[r][1] += lv.x * zv[0].y + lv.y * zv[1].y + lv.z * zv[2].y + lv.w * zv[3].y;
            acc[r][2] += lv.x * zv[0].z + lv.y * zv[1].z + lv.z * zv[2].z + lv.w * zv[3].z;
            acc[r][3] += lv.x * zv[0].w + lv.y * zv[1].w + lv.z * zv[2].w + lv.w * zv[3].w;
        }
    }

    // ---- epilogue: add m, scatter ----
    #pragma unroll
    for (int r = 0; r < 4; ++r) {
        int j = jq * 32 + jg + 8 * r;
        float mm = m[ck * N_Z + j];
        #pragma unroll
        for (int s = 0; s < 4; ++s) {
            int sl = sl4 + s;
            if (sl < ns) {
                int samp = order[base + s0 + sl];
                out[(size_t)samp * N_Z + j] = acc[r][s] + mm;
            }
        }
    }
}

extern "C" void kernel_launch(void* const* d_in, const int* in_sizes, int n_in,
                              void* d_out, int out_size, void* d_ws, size_t ws_size,
                              hipStream_t stream)
{
    const float* z      = (const float*)d_in[0];
    const int*   y      = (const int*)d_in[1];
    const float* gumbel = (const float*)d_in[2];
    const float* m      = (const float*)d_in[3];
    const float* L      = (const float*)d_in[4];
    const float* logits = (const float*)d_in[5];
    float* out = (float*)d_out;

    const int bs = in_sizes[0] / N_Z;  // 8192

    // workspace layout (ints)
    int* counts = (int*)d_ws;           // 128
    int* order  = counts + 128;         // N_CK * CAP

    hipMemsetAsync(counts, 0, 128 * sizeof(int), stream);
    k_select<<<(bs + 255) / 256, 256, 0, stream>>>(y, gumbel, logits, counts, order, bs);
    k_gemm<<<dim3(N_CK, 4, MAXCHUNK), 128, 0, stream>>>(z, m, L, counts, order, out, bs);
}

// Round 8
// 98.030 us; speedup vs baseline: 1.1139x; 1.0333x over previous
//
#include <hip/hip_runtime.h>

// Forward collapse:
//   c = y[b]; k = argmax_k(logits[c,k] + gumbel[c,b,k]) (first max)
//   x[b,:] = L[c,k] @ z[b,:] + m[c,k,:]
//
// Round 8: round-7 structure with the scan-loop bug fixed (scan was written
// for 256 threads; k_gemm has 128 -> half the samples were never scanned).
//   K1: ck_arr[b] = selected ck (uint8, 8 KB)
//   K2: grid (100 ck, 4 jq), 128 thr, 48 KB LDS (3 blocks/CU, 400 blocks all
//       co-resident). Each block scans the 8 KB ck_arr (L2-broadcast) into an
//       LDS list, stages its rotated L-quarter ONCE, then loops sample chunks.

#define N_Z 128
#define N_COMP 10
#define N_CLASSES 10
#define N_CK (N_CLASSES * N_COMP)
#define TB 64            // samples per chunk
#define LIST_CAP 256     // bucket capacity (mean 82; overflow prob ~0)

// ---------------- K1: per-sample component select (atomic-free) ----------------
__global__ __launch_bounds__(256) void k_select(
    const int* __restrict__ y, const float* __restrict__ gumbel,
    const float* __restrict__ logits, unsigned char* __restrict__ ck_arr, int bs)
{
    int b = blockIdx.x * 256 + threadIdx.x;
    if (b >= bs) return;
    int c = y[b];
    const float* g  = gumbel + ((size_t)c * bs + b) * N_COMP;
    const float* lg = logits + c * N_COMP;
    float best = g[0] + lg[0];
    int bi = 0;
    #pragma unroll
    for (int k = 1; k < N_COMP; ++k) {
        float s = g[k] + lg[k];
        if (s > best) { best = s; bi = k; }  // strict > == first-max (jnp.argmax)
    }
    ck_arr[b] = (unsigned char)(c * N_COMP + bi);
}

// ---------------- K2: per-bucket batched GEMV ----------------
// Block = (ck, j-quarter). Thread tile 4j (stride-8) x 4s.
// Ls rotated: Ls[jl*128 + ((i+4*jl)&127)] = L[jq*32+jl][i]  (conflict-free reads)
// zs transposed: zs[i*TB + sl] = z[sample sl][i]             (conflict-free reads)
__global__ __launch_bounds__(128) void k_gemm(
    const float* __restrict__ z, const float* __restrict__ m,
    const float* __restrict__ L, const unsigned char* __restrict__ ck_arr,
    float* __restrict__ out, int bs)
{
    const int ck = blockIdx.x;
    const int jq = blockIdx.y;   // j range [jq*32, jq*32+32)

    __shared__ __align__(16) float Ls[32 * 128];   // 16 KB rotated quarter
    __shared__ __align__(16) float zs[N_Z * TB];   // 32 KB transposed z
    __shared__ int list[LIST_CAP];                 // 1 KB
    __shared__ int cnt;

    const int t = threadIdx.x;
    if (t == 0) cnt = 0;

    // ---- stage L quarter (32 rows x 128 = 1024 float4s, 128 thr x 8) ----
    {
        const float4* Lg4 = (const float4*)(L + ((size_t)ck * N_Z + jq * 32) * N_Z);
        #pragma unroll
        for (int p = 0; p < 8; ++p) {
            int f  = p * 128 + t;      // float4 index in the 32x128 quarter
            int jl = f >> 5;           // local row 0..31
            int fi = f & 31;           // float4 within row
            float4 v = Lg4[f];
            int col = ((fi << 2) + 4 * jl) & 127;
            *(float4*)&Ls[jl * 128 + col] = v;
        }
    }
    __syncthreads();   // cnt=0 visible

    // ---- scan ck_arr (8 KB = 512 uint4s, 128 thr x 4) -> LDS match list ----
    {
        const uint4* ck4 = (const uint4*)ck_arr;   // 16 samples per load
        #pragma unroll
        for (int p = 0; p < 4; ++p) {              // 512 / 128 = 4
            int idx = p * 128 + t;
            uint4 v = ck4[idx];
            int b0 = idx * 16;
            unsigned w[4] = {v.x, v.y, v.z, v.w};
            #pragma unroll
            for (int q = 0; q < 4; ++q) {
                #pragma unroll
                for (int e = 0; e < 4; ++e) {
                    if (((w[q] >> (8 * e)) & 0xFFu) == (unsigned)ck) {
                        int p2 = atomicAdd(&cnt, 1);
                        if (p2 < LIST_CAP) list[p2] = b0 + q * 4 + e;
                    }
                }
            }
        }
    }
    __syncthreads();

    const int n = min(cnt, LIST_CAP);

    const int jg  = t & 7;     // 8 j-groups, local rows jl = jg + 8r (r<4)
    const int sg  = t >> 3;    // 16 s-groups x 4 samples
    const int sl4 = sg << 2;
    const int ssl = t & 63;    // staging: sample lane
    const int sih = t >> 6;    // staging: i-half

    for (int s0 = 0; s0 < n; s0 += TB) {
        const int ns = min(TB, n - s0);

        // ---- stage z transposed for this chunk ----
        {
            int samp = list[s0 + (ssl < ns ? ssl : 0)];  // pad lanes reuse slot 0
            const float* zg = z + (size_t)samp * N_Z + sih * 64;
            #pragma unroll
            for (int q = 0; q < 16; ++q) {
                float4 v = *(const float4*)(zg + q * 4);
                int i = sih * 64 + q * 4;
                zs[(i + 0) * TB + ssl] = v.x;
                zs[(i + 1) * TB + ssl] = v.y;
                zs[(i + 2) * TB + ssl] = v.z;
                zs[(i + 3) * TB + ssl] = v.w;
            }
        }
        __syncthreads();

        float acc[4][4] = {};
        #pragma unroll 2
        for (int i = 0; i < N_Z; i += 4) {
            float4 zv[4];
            #pragma unroll
            for (int ri = 0; ri < 4; ++ri)
                zv[ri] = *(const float4*)&zs[(i + ri) * TB + sl4];
            #pragma unroll
            for (int r = 0; r < 4; ++r) {
                int jl  = jg + 8 * r;
                int col = (i + 4 * jl) & 127;
                float4 lv = *(const float4*)&Ls[jl * 128 + col];
                acc[r][0] += lv.x * zv[0].x + lv.y * zv[1].x + lv.z * zv[2].x + lv.w * zv[3].x;
                acc[r][1] += lv.x * zv[0].y + lv.y * zv[1].y + lv.z * zv[2].y + lv.w * zv[3].y;
                acc[r][2] += lv.x * zv[0].z + lv.y * zv[1].z + lv.z * zv[2].z + lv.w * zv[3].z;
                acc[r][3] += lv.x * zv[0].w + lv.y * zv[1].w + lv.z * zv[2].w + lv.w * zv[3].w;
            }
        }

        // ---- epilogue: add m, scatter ----
        #pragma unroll
        for (int r = 0; r < 4; ++r) {
            int j = jq * 32 + jg + 8 * r;
            float mm = m[ck * N_Z + j];
            #pragma unroll
            for (int s = 0; s < 4; ++s) {
                int sl = sl4 + s;
                if (sl < ns) {
                    int samp = list[s0 + sl];
                    out[(size_t)samp * N_Z + j] = acc[r][s] + mm;
                }
            }
        }
        __syncthreads();   // before next chunk overwrites zs
    }
}

extern "C" void kernel_launch(void* const* d_in, const int* in_sizes, int n_in,
                              void* d_out, int out_size, void* d_ws, size_t ws_size,
                              hipStream_t stream)
{
    const float* z      = (const float*)d_in[0];
    const int*   y      = (const int*)d_in[1];
    const float* gumbel = (const float*)d_in[2];
    const float* m      = (const float*)d_in[3];
    const float* L      = (const float*)d_in[4];
    const float* logits = (const float*)d_in[5];
    float* out = (float*)d_out;

    const int bs = in_sizes[0] / N_Z;  // 8192

    unsigned char* ck_arr = (unsigned char*)d_ws;   // bs bytes

    k_select<<<(bs + 255) / 256, 256, 0, stream>>>(y, gumbel, logits, ck_arr, bs);
    k_gemm<<<dim3(N_CK, 4), 128, 0, stream>>>(z, m, L, ck_arr, out, bs);
}

// Round 9
// 90.531 us; speedup vs baseline: 1.2062x; 1.0828x over previous
//
#include <hip/hip_runtime.h>

// Forward collapse:
//   c = y[b]; k = argmax_k(logits[c,k] + gumbel[c,b,k]) (first max)
//   x[b,:] = L[c,k] @ z[b,:] + m[c,k,:]
//
// Round 9: two nodes. k_gemm rebuilt for occupancy: 256 thr, 62 KB LDS ->
// 2 blocks/CU (8 waves/CU), grid (100 ck, 2 jh, 2 sample-halves) = 400 blocks.
// Each block scans its 4 KB half of ck_arr, stages rotated L-half once,
// z in row layout with pitch 132 (conflict-free), typically one 56-sample chunk.

#define N_Z 128
#define N_COMP 10
#define N_CLASSES 10
#define N_CK (N_CLASSES * N_COMP)
#define TB 56            // samples per chunk
#define ZPITCH 132       // zs row pitch in floats (bank-spread: 132 = 4 mod 32, 528B = 33*16B)
#define LIST_CAP 256

// ---------------- K1: per-sample component select (atomic-free) ----------------
__global__ __launch_bounds__(64) void k_select(
    const int* __restrict__ y, const float* __restrict__ gumbel,
    const float* __restrict__ logits, unsigned char* __restrict__ ck_arr, int bs)
{
    int b = blockIdx.x * 64 + threadIdx.x;
    if (b >= bs) return;
    int c = y[b];
    const float* g  = gumbel + ((size_t)c * bs + b) * N_COMP;
    const float* lg = logits + c * N_COMP;
    float best = g[0] + lg[0];
    int bi = 0;
    #pragma unroll
    for (int k = 1; k < N_COMP; ++k) {
        float s = g[k] + lg[k];
        if (s > best) { best = s; bi = k; }  // strict > == first-max (jnp.argmax)
    }
    ck_arr[b] = (unsigned char)(c * N_COMP + bi);
}

// ---------------- K2: per-bucket batched GEMV ----------------
// Block = (ck, j-half, sample-half). 256 thr. Thread tile 4j (stride-16) x 4s.
// Ls rotated: Ls[jl*128 + ((i+4*jl)&127)] = L[jh*64+jl][i]
// zs rows:    zs[sl*ZPITCH + i] = z[sample sl][i]
__global__ __launch_bounds__(256) void k_gemm(
    const float* __restrict__ z, const float* __restrict__ m,
    const float* __restrict__ L, const unsigned char* __restrict__ ck_arr,
    float* __restrict__ out, int bs)
{
    const int ck = blockIdx.x;
    const int jh = blockIdx.y;   // j range [jh*64, jh*64+64)
    const int bh = blockIdx.z;   // sample half: [bh*bs/2, (bh+1)*bs/2)

    __shared__ __align__(16) float Ls[64 * 128];      // 32 KB
    __shared__ __align__(16) float zs[TB * ZPITCH];   // 28.9 KB
    __shared__ int list[LIST_CAP];                    // 1 KB
    __shared__ int cnt;

    const int t = threadIdx.x;
    if (t == 0) cnt = 0;

    // ---- stage L half (64 rows x 128 = 2048 float4s, 256 thr x 8) ----
    {
        const float4* Lg4 = (const float4*)(L + ((size_t)ck * N_Z + jh * 64) * N_Z);
        #pragma unroll
        for (int p = 0; p < 8; ++p) {
            int f  = p * 256 + t;      // float4 index in the 64x128 half
            int jl = f >> 5;           // local row 0..63
            int fi = f & 31;
            float4 v = Lg4[f];
            int col = ((fi << 2) + 4 * jl) & 127;
            *(float4*)&Ls[jl * 128 + col] = v;
        }
    }
    __syncthreads();   // cnt=0 visible

    // ---- scan this block's half of ck_arr (4 KB = 256 uint4, 1/thread) ----
    {
        const int half = bs >> 1;                       // 4096
        const uint4* ck4 = (const uint4*)(ck_arr + bh * half);
        int idx = t;                                    // 256 uint4s, one each
        uint4 v = ck4[idx];
        int b0 = bh * half + idx * 16;
        unsigned w[4] = {v.x, v.y, v.z, v.w};
        #pragma unroll
        for (int q = 0; q < 4; ++q) {
            #pragma unroll
            for (int e = 0; e < 4; ++e) {
                if (((w[q] >> (8 * e)) & 0xFFu) == (unsigned)ck) {
                    int p2 = atomicAdd(&cnt, 1);
                    if (p2 < LIST_CAP) list[p2] = b0 + q * 4 + e;
                }
            }
        }
    }
    __syncthreads();

    const int n = min(cnt, LIST_CAP);   // ~41 typical

    const int jg  = t & 15;    // 16 j-groups, local rows jl = jg + 16r (r<4)
    const int sg  = t >> 4;    // 16 s-groups x 4 samples (slots 56..63 always dead)
    const int sl4 = sg << 2;

    for (int s0 = 0; s0 < n; s0 += TB) {
        const int ns = min(TB, n - s0);

        // ---- stage z rows: zs[sl*ZPITCH + i] (TB*32 = 1792 f4, 256 thr x 7) ----
        #pragma unroll
        for (int p = 0; p < 7; ++p) {
            int f  = p * 256 + t;        // 0..1791
            int sl = f >> 5;             // 0..55
            int fi = f & 31;
            int samp = list[s0 + (sl < ns ? sl : 0)];
            float4 v = *(const float4*)(z + (size_t)samp * N_Z + fi * 4);
            *(float4*)&zs[sl * ZPITCH + fi * 4] = v;
        }
        __syncthreads();

        if (sl4 < ns) {
            float acc[4][4] = {};
            #pragma unroll 2
            for (int i = 0; i < N_Z; i += 4) {
                float4 zv[4];
                #pragma unroll
                for (int s = 0; s < 4; ++s)
                    zv[s] = *(const float4*)&zs[(sl4 + s) * ZPITCH + i];
                #pragma unroll
                for (int r = 0; r < 4; ++r) {
                    int jl  = jg + 16 * r;
                    int col = (i + 4 * jl) & 127;
                    float4 lv = *(const float4*)&Ls[jl * 128 + col];
                    acc[r][0] += lv.x * zv[0].x + lv.y * zv[0].y + lv.z * zv[0].z + lv.w * zv[0].w;
                    acc[r][1] += lv.x * zv[1].x + lv.y * zv[1].y + lv.z * zv[1].z + lv.w * zv[1].w;
                    acc[r][2] += lv.x * zv[2].x + lv.y * zv[2].y + lv.z * zv[2].z + lv.w * zv[2].w;
                    acc[r][3] += lv.x * zv[3].x + lv.y * zv[3].y + lv.z * zv[3].z + lv.w * zv[3].w;
                }
            }
            // ---- epilogue: add m, scatter ----
            #pragma unroll
            for (int r = 0; r < 4; ++r) {
                int j = jh * 64 + jg + 16 * r;
                float mm = m[ck * N_Z + j];
                #pragma unroll
                for (int s = 0; s < 4; ++s) {
                    int sl = sl4 + s;
                    if (sl < ns) {
                        int samp = list[s0 + sl];
                        out[(size_t)samp * N_Z + j] = acc[r][s] + mm;
                    }
                }
            }
        }
        __syncthreads();   // before next chunk overwrites zs
    }
}

extern "C" void kernel_launch(void* const* d_in, const int* in_sizes, int n_in,
                              void* d_out, int out_size, void* d_ws, size_t ws_size,
                              hipStream_t stream)
{
    const float* z      = (const float*)d_in[0];
    const int*   y      = (const int*)d_in[1];
    const float* gumbel = (const float*)d_in[2];
    const float* m      = (const float*)d_in[3];
    const float* L      = (const float*)d_in[4];
    const float* logits = (const float*)d_in[5];
    float* out = (float*)d_out;

    const int bs = in_sizes[0] / N_Z;  // 8192

    unsigned char* ck_arr = (unsigned char*)d_ws;   // bs bytes

    k_select<<<(bs + 63) / 64, 64, 0, stream>>>(y, gumbel, logits, ck_arr, bs);
    k_gemm<<<dim3(N_CK, 2, 2), 256, 0, stream>>>(z, m, L, ck_arr, out, bs);
}